// Round 20
// baseline (97.812 us; speedup 1.0000x reference)
//
#include <hip/hip_runtime.h>
#include <hip/hip_bf16.h>

// PartitionedNormalization: per-domain BN stats (training mode) + affine.
// out[B][128] f32 = (gg+dg[s])*(x-mean[s])*rsqrt(var[s]+eps) + (gb+db[s])
//
// R20: R19 sort reverted (97.8us; sort+gather > DS saving). vs R18 single
// change: pass-1 regions are WAVE-private (1 row/wave, float2/lane) ->
// 32KB LDS/block -> 4 blocks/CU = 16 waves/CU (2x TLP of R18).

#define DIM 128
#define NDOM 8
#define PENT (NDOM + 2 * NDOM * DIM)  // 8 counts + 1024 sums + 1024 sqsums = 2056
#define EPSV 1e-3f
#define WREG 2048  // per-wave region (floats): sums[8][128] | sqs[8][128] = 8KB

// ---------------- pass 1: wave-private LDS accumulation, 1 row/wave ----------------
__global__ __launch_bounds__(256) void pn_reduce(const float2* __restrict__ x2,
                                                 const int* __restrict__ seg,
                                                 float* __restrict__ partials,
                                                 int rowsPerBlock) {
  __shared__ float acc[4 * WREG];  // 32 KB -> 4 blocks/CU (16 waves/CU)
  __shared__ float lcnt[NDOM];
  const int tid = threadIdx.x;
  const int w = tid >> 6;  // wave 0..3
  const int l = tid & 63;  // lane; covers cols 2l, 2l+1
  float* reg = acc + w * WREG;  // wave private

  for (int i = tid; i < WREG; i += 256)
    ((float4*)acc)[i] = make_float4(0.f, 0.f, 0.f, 0.f);
  if (tid < NDOM) lcnt[tid] = 0.f;
  __syncthreads();

  const int rowsPerWave = rowsPerBlock >> 2;  // 64 at NB=1024
  const int row0 = blockIdx.x * rowsPerBlock + w * rowsPerWave;

#define RMW(S, V)                                    \
  {                                                  \
    float* bs = reg + (S) * 128 + l * 2;             \
    float* bq = bs + NDOM * DIM;                     \
    float2 os = *(float2*)bs;                        \
    float2 oq = *(float2*)bq;                        \
    os.x += (V).x;                                   \
    os.y += (V).y;                                   \
    oq.x = fmaf((V).x, (V).x, oq.x);                 \
    oq.y = fmaf((V).y, (V).y, oq.y);                 \
    *(float2*)bs = os;                               \
    *(float2*)bq = oq;                               \
  }
  for (int it = 0; it < rowsPerWave; it += 8) {
    const int r = row0 + it;
    const int4 sgA = *(const int4*)(seg + r);      // rows r..r+3
    const int4 sgB = *(const int4*)(seg + r + 4);  // rows r+4..r+7
    // 8 independent 512B row loads in flight before any RMW
    const float2 v0 = x2[(size_t)(r + 0) * 64 + l];
    const float2 v1 = x2[(size_t)(r + 1) * 64 + l];
    const float2 v2 = x2[(size_t)(r + 2) * 64 + l];
    const float2 v3 = x2[(size_t)(r + 3) * 64 + l];
    const float2 v4 = x2[(size_t)(r + 4) * 64 + l];
    const float2 v5 = x2[(size_t)(r + 5) * 64 + l];
    const float2 v6 = x2[(size_t)(r + 6) * 64 + l];
    const float2 v7 = x2[(size_t)(r + 7) * 64 + l];
    RMW(sgA.x, v0)
    RMW(sgA.y, v1)
    RMW(sgA.z, v2)
    RMW(sgA.w, v3)
    RMW(sgB.x, v4)
    RMW(sgB.y, v5)
    RMW(sgB.z, v6)
    RMW(sgB.w, v7)
  }
#undef RMW
  __syncthreads();

  for (int i = tid; i < rowsPerBlock; i += 256)
    atomicAdd(&lcnt[seg[blockIdx.x * rowsPerBlock + i]], 1.f);
  __syncthreads();

  float* outp = partials + (size_t)blockIdx.x * PENT;
  if (tid < NDOM) outp[tid] = lcnt[tid];
  for (int i = tid; i < 2 * NDOM * DIM; i += 256) {
    float v = 0.f;
#pragma unroll
    for (int rr = 0; rr < 4; ++rr) v += acc[rr * WREG + i];
    outp[NDOM + i] = v;
  }
}

// ---------------- pass 2a: reduce NB partial rows -> 64 ----------------
__global__ __launch_bounds__(256) void pn_reduce2(const float* __restrict__ partials,
                                                  float* __restrict__ partials2,
                                                  int NB) {
  const int b = blockIdx.x;  // 0..63
  const int per = NB >> 6;
  const int b0 = b * per;
  const int tid = threadIdx.x;
  float acc[9];
#pragma unroll
  for (int i = 0; i < 9; ++i) acc[i] = 0.f;
  for (int j = b0; j < b0 + per; ++j) {
    const float* p = partials + (size_t)j * PENT;
#pragma unroll
    for (int i = 0; i < 9; ++i) {
      const int e = tid + i * 256;
      if (e < PENT) acc[i] += p[e];
    }
  }
  float* o = partials2 + (size_t)b * PENT;
#pragma unroll
  for (int i = 0; i < 9; ++i) {
    const int e = tid + i * 256;
    if (e < PENT) o[e] = acc[i];
  }
}

// ---------------- pass 2b: final reduce + scale/shift table (4 blocks) ----------------
__global__ __launch_bounds__(256) void pn_finalize(const float* __restrict__ partials2,
                                                   const float* __restrict__ gg,
                                                   const float* __restrict__ gb,
                                                   const float* __restrict__ dg,
                                                   const float* __restrict__ db,
                                                   float* __restrict__ stats) {
  const int t = blockIdx.x * 256 + threadIdx.x;  // (k = t>>7, d = t&127)
  const int k = t >> 7;
  const int d = t & (DIM - 1);
  float c = 0.f, s = 0.f, q = 0.f;
  for (int j = 0; j < 64; ++j) {
    const float* p = partials2 + (size_t)j * PENT;
    c += p[k];
    s += p[NDOM + t];
    q += p[NDOM + NDOM * DIM + t];
  }
  const float n = fmaxf(c, 1.f);
  const float mean = s / n;
  const float var = fmaxf(q / n - mean * mean, 0.f);
  const float rstd = rsqrtf(var + EPSV);
  const float scale = (gg[d] + dg[t]) * rstd;  // dg[k*128+d] == dg[t]
  const float shift = (gb[d] + db[t]) - scale * mean;
  stats[t] = scale;
  stats[NDOM * DIM + t] = shift;
}

// ---------------- pass 3: normalize (one-shot, 1 float4/thread) ----------------
__global__ __launch_bounds__(256) void pn_apply(const float* __restrict__ x,
                                                const int* __restrict__ seg,
                                                const float* __restrict__ stats,
                                                float* __restrict__ out) {
  const int g = blockIdx.x * 256 + threadIdx.x;  // float4 index
  const int row = g >> 5;                        // 32 float4 per row
  const int c4 = g & 31;
  const int s = seg[row];
  const float4 xv = ((const float4*)x)[g];
  const float4 a = ((const float4*)(stats + s * DIM))[c4];
  const float4 b = ((const float4*)(stats + NDOM * DIM + s * DIM))[c4];
  float4 o;
  o.x = fmaf(xv.x, a.x, b.x);
  o.y = fmaf(xv.y, a.y, b.y);
  o.z = fmaf(xv.z, a.z, b.z);
  o.w = fmaf(xv.w, a.w, b.w);
  ((float4*)out)[g] = o;
}

extern "C" void kernel_launch(void* const* d_in, const int* in_sizes, int n_in,
                              void* d_out, int out_size, void* d_ws, size_t ws_size,
                              hipStream_t stream) {
  const float* x = (const float*)d_in[0];
  const float* gg = (const float*)d_in[1];
  const float* gb = (const float*)d_in[2];
  const float* dg = (const float*)d_in[3];
  const float* db = (const float*)d_in[4];
  const int* seg = (const int*)d_in[5];
  float* out = (float*)d_out;
  const int B = in_sizes[5];  // 262144

  // workspace: partials[NB][PENT] | partials2[64][PENT] | stats[2048]
  const int NB = 1024;  // 4 blocks/CU (32KB LDS), one co-resident round
  float* partials = (float*)d_ws;
  float* partials2 = partials + (size_t)NB * PENT;
  float* stats = partials2 + (size_t)64 * PENT;

  const int rpb = B / NB;  // 256 rows/block; 64 contiguous rows/wave

  pn_reduce<<<NB, 256, 0, stream>>>((const float2*)x, seg, partials, rpb);
  pn_reduce2<<<64, 256, 0, stream>>>(partials, partials2, NB);
  pn_finalize<<<4, 256, 0, stream>>>(partials2, gg, gb, dg, db, stats);

  const int nblk = (B * (DIM / 4)) / 256;  // 32768
  pn_apply<<<nblk, 256, 0, stream>>>(x, seg, stats, out);
}